// Round 1
// baseline (299.252 us; speedup 1.0000x reference)
//
#include <hip/hip_runtime.h>
#include <hip/hip_bf16.h>

typedef short short8 __attribute__((ext_vector_type(8)));
typedef float f32x4 __attribute__((ext_vector_type(4)));

#define N_SPK 1024
#define M_UTT 40
#define D_FEAT 768
#define NROWS (N_SPK * M_UTT)

// ---------------- Kernel 1: L2-normalize each utterance row ----------------
__global__ __launch_bounds__(256) void k_normalize(const float* __restrict__ x,
                                                   __hip_bfloat16* __restrict__ xn) {
  const int row = blockIdx.x;                 // n*M + m
  const float* xr = x + (size_t)row * D_FEAT;
  const int t = threadIdx.x;
  const float v0 = xr[t], v1 = xr[t + 256], v2 = xr[t + 512];
  float ss = v0 * v0 + v1 * v1 + v2 * v2;
#pragma unroll
  for (int d = 1; d < 64; d <<= 1) ss += __shfl_xor(ss, d, 64);
  __shared__ float wsum[4];
  const int lane = t & 63, wv = t >> 6;
  if (lane == 0) wsum[wv] = ss;
  __syncthreads();
  const float tot = wsum[0] + wsum[1] + wsum[2] + wsum[3];
  const float inv = 1.0f / fmaxf(sqrtf(tot), 1e-12f);
  __hip_bfloat16* o = xn + (size_t)row * D_FEAT;
  o[t]       = __float2bfloat16(v0 * inv);
  o[t + 256] = __float2bfloat16(v1 * inv);
  o[t + 512] = __float2bfloat16(v2 * inv);
}

// ---------------- Kernel 2: inclusive centroids (mean over M) ----------------
__global__ __launch_bounds__(256) void k_centroid(const __hip_bfloat16* __restrict__ xn,
                                                  __hip_bfloat16* __restrict__ cc) {
  const int n = blockIdx.x;
  const int t = threadIdx.x;
  const __hip_bfloat16* base = xn + (size_t)n * M_UTT * D_FEAT;
#pragma unroll
  for (int c = t; c < D_FEAT; c += 256) {
    float s = 0.f;
#pragma unroll 8
    for (int m = 0; m < M_UTT; ++m) s += __bfloat162float(base[(size_t)m * D_FEAT + c]);
    cc[(size_t)n * D_FEAT + c] = __float2bfloat16(s * (1.0f / M_UTT));
  }
}

// ---------------- Kernel 3: GEMM (64 rows x 1024 cols, K=768) + fused LSE ----------------
// block = 512 threads = 8 waves; wave w owns columns [w*128, w*128+128)
// per wave: 4 row-frags x 8 col-frags of mfma_f32_16x16x32_bf16
__global__ __launch_bounds__(512) void k_gemm_loss(
    const __hip_bfloat16* __restrict__ XN, const __hip_bfloat16* __restrict__ CC,
    const float* __restrict__ wp, const float* __restrict__ bp,
    float* __restrict__ rowloss) {
  const int tid  = threadIdx.x;
  const int wave = tid >> 6;
  const int lane = tid & 63;
  const int l16  = lane & 15;
  const int lg   = lane >> 4;
  const int rowbase = blockIdx.x * 64;
  const int colbase = wave * 128;

  f32x4 acc[4][8];
#pragma unroll
  for (int i = 0; i < 4; ++i)
#pragma unroll
    for (int j = 0; j < 8; ++j) acc[i][j] = (f32x4){0.f, 0.f, 0.f, 0.f};

  const short* A = (const short*)XN;
  const short* B = (const short*)CC;
  const short* aptr[4];
  const short* bptr[8];
#pragma unroll
  for (int i = 0; i < 4; ++i)
    aptr[i] = A + (size_t)(rowbase + i * 16 + l16) * D_FEAT + lg * 8;
#pragma unroll
  for (int j = 0; j < 8; ++j)
    bptr[j] = B + (size_t)(colbase + j * 16 + l16) * D_FEAT + lg * 8;

  for (int kk = 0; kk < D_FEAT; kk += 32) {
    short8 av[4], bv[8];
#pragma unroll
    for (int i = 0; i < 4; ++i) { av[i] = *(const short8*)aptr[i]; aptr[i] += 32; }
#pragma unroll
    for (int j = 0; j < 8; ++j) { bv[j] = *(const short8*)bptr[j]; bptr[j] += 32; }
#pragma unroll
    for (int i = 0; i < 4; ++i)
#pragma unroll
      for (int j = 0; j < 8; ++j)
        acc[i][j] = __builtin_amdgcn_mfma_f32_16x16x32_bf16(av[i], bv[j], acc[i][j], 0, 0, 0);
  }

  const float wsc = *wp;
  const float bia = *bp;

  __shared__ float red[8][64];
  __shared__ float gmax[64];
  __shared__ float picked[64];

  // diagonal fixup: own-speaker column uses exclusive centroid:
  // diag = (M*sim - ||xn||^2)/(M-1), with ||xn||^2 == 1
#pragma unroll
  for (int i = 0; i < 4; ++i) {
#pragma unroll
    for (int rr = 0; rr < 4; ++rr) {
      const int lrow = i * 16 + lg * 4 + rr;
      const int n = (rowbase + lrow) / M_UTT;
#pragma unroll
      for (int j = 0; j < 8; ++j) {
        const int gcol = colbase + j * 16 + l16;
        if (gcol == n) {
          const float adj = (40.f * acc[i][j][rr] - 1.f) * (1.f / 39.f);
          acc[i][j][rr] = adj;
          picked[lrow] = fmaf(wsc, adj, bia);
        }
      }
    }
  }

  // per-row max of logits
#pragma unroll
  for (int i = 0; i < 4; ++i) {
#pragma unroll
    for (int rr = 0; rr < 4; ++rr) {
      float v = -1e30f;
#pragma unroll
      for (int j = 0; j < 8; ++j) v = fmaxf(v, fmaf(wsc, acc[i][j][rr], bia));
#pragma unroll
      for (int d = 1; d < 16; d <<= 1) v = fmaxf(v, __shfl_xor(v, d, 64));
      if (l16 == 0) red[wave][i * 16 + lg * 4 + rr] = v;
    }
  }
  __syncthreads();
  if (tid < 64) {
    float v = red[0][tid];
#pragma unroll
    for (int wv = 1; wv < 8; ++wv) v = fmaxf(v, red[wv][tid]);
    gmax[tid] = v;
  }
  __syncthreads();

  // per-row sum of exp(logit - max)
#pragma unroll
  for (int i = 0; i < 4; ++i) {
#pragma unroll
    for (int rr = 0; rr < 4; ++rr) {
      const int lrow = i * 16 + lg * 4 + rr;
      const float gm = gmax[lrow];
      float s = 0.f;
#pragma unroll
      for (int j = 0; j < 8; ++j) s += expf(fmaf(wsc, acc[i][j][rr], bia) - gm);
#pragma unroll
      for (int d = 1; d < 16; d <<= 1) s += __shfl_xor(s, d, 64);
      if (l16 == 0) red[wave][lrow] = s;
    }
  }
  __syncthreads();
  if (tid < 64) {
    float tot = 0.f;
#pragma unroll
    for (int wv = 0; wv < 8; ++wv) tot += red[wv][tid];
    const float lse = gmax[tid] + logf(tot);
    rowloss[rowbase + tid] = lse - picked[tid];
  }
}

// ---------------- Kernel 4: mean over all 40960 rows ----------------
__global__ __launch_bounds__(512) void k_reduce(const float* __restrict__ rowloss,
                                                float* __restrict__ out) {
  const int t = threadIdx.x;
  double s = 0.0;
  for (int i = t; i < NROWS; i += 512) s += (double)rowloss[i];
  __shared__ double sm[512];
  sm[t] = s;
  __syncthreads();
  for (int off = 256; off > 0; off >>= 1) {
    if (t < off) sm[t] += sm[t + off];
    __syncthreads();
  }
  if (t == 0) out[0] = (float)(sm[0] / (double)NROWS);
}

extern "C" void kernel_launch(void* const* d_in, const int* in_sizes, int n_in,
                              void* d_out, int out_size, void* d_ws, size_t ws_size,
                              hipStream_t stream) {
  const float* x = (const float*)d_in[0];
  const float* w = (const float*)d_in[1];
  const float* b = (const float*)d_in[2];
  char* ws = (char*)d_ws;
  __hip_bfloat16* xn = (__hip_bfloat16*)ws;
  __hip_bfloat16* cc = (__hip_bfloat16*)(ws + (size_t)NROWS * D_FEAT * 2);
  float* rowloss = (float*)(ws + (size_t)NROWS * D_FEAT * 2 + (size_t)N_SPK * D_FEAT * 2);
  float* out = (float*)d_out;

  k_normalize<<<NROWS, 256, 0, stream>>>(x, xn);
  k_centroid<<<N_SPK, 256, 0, stream>>>(xn, cc);
  k_gemm_loss<<<NROWS / 64, 512, 0, stream>>>(xn, cc, w, b, rowloss);
  k_reduce<<<1, 512, 0, stream>>>(rowloss, out);
}

// Round 2
// 161.054 us; speedup vs baseline: 1.8581x; 1.8581x over previous
//
#include <hip/hip_runtime.h>
#include <hip/hip_bf16.h>

typedef short short8 __attribute__((ext_vector_type(8)));
typedef float f32x4 __attribute__((ext_vector_type(4)));

#define N_SPK 1024
#define M_UTT 40
#define D_FEAT 768
#define NROWS (N_SPK * M_UTT)
#define LOG2E 1.44269504088896340736f
#define LN2   0.69314718055994530942f

#define BM 128
#define BN 128
#define BK 64
#define KT (D_FEAT / BK)  // 12

// ---------------- Kernel 1: L2-normalize each utterance row ----------------
__global__ __launch_bounds__(256) void k_normalize(const float* __restrict__ x,
                                                   __hip_bfloat16* __restrict__ xn) {
  const int row = blockIdx.x;
  const float* xr = x + (size_t)row * D_FEAT;
  const int t = threadIdx.x;
  const float v0 = xr[t], v1 = xr[t + 256], v2 = xr[t + 512];
  float ss = v0 * v0 + v1 * v1 + v2 * v2;
#pragma unroll
  for (int d = 1; d < 64; d <<= 1) ss += __shfl_xor(ss, d, 64);
  __shared__ float wsum[4];
  const int lane = t & 63, wv = t >> 6;
  if (lane == 0) wsum[wv] = ss;
  __syncthreads();
  const float tot = wsum[0] + wsum[1] + wsum[2] + wsum[3];
  const float inv = 1.0f / fmaxf(sqrtf(tot), 1e-12f);
  __hip_bfloat16* o = xn + (size_t)row * D_FEAT;
  o[t]       = __float2bfloat16(v0 * inv);
  o[t + 256] = __float2bfloat16(v1 * inv);
  o[t + 512] = __float2bfloat16(v2 * inv);
}

// ---------------- Kernel 2: inclusive centroids (mean over M) ----------------
__global__ __launch_bounds__(256) void k_centroid(const __hip_bfloat16* __restrict__ xn,
                                                  __hip_bfloat16* __restrict__ cc) {
  const int n = blockIdx.x;
  const int t = threadIdx.x;
  const __hip_bfloat16* base = xn + (size_t)n * M_UTT * D_FEAT;
#pragma unroll
  for (int c = t; c < D_FEAT; c += 256) {
    float s = 0.f;
#pragma unroll 8
    for (int m = 0; m < M_UTT; ++m) s += __bfloat162float(base[(size_t)m * D_FEAT + c]);
    cc[(size_t)n * D_FEAT + c] = __float2bfloat16(s * (1.0f / M_UTT));
  }
}

// ---------------- Kernel 3: 128x128 GEMM tiles + per-row partial LSE ----------------
// grid 2560 = 320 row-blocks x 8 col-blocks, 256 threads (4 waves, 2x2 of 64x64)
// A,B double-buffered in LDS (global_load_lds w16, XOR-swizzled layout)
__global__ __launch_bounds__(256) void k_gemm_part(
    const __hip_bfloat16* __restrict__ XN, const __hip_bfloat16* __restrict__ CC,
    const float* __restrict__ wp, const float* __restrict__ bp,
    float2* __restrict__ ppart, float* __restrict__ picked2) {

  // As[0]@0, Bs[0]@16K, As[1]@32K, Bs[1]@48K; epilogue red[] reuses As[0]
  __shared__ char smem[65536];

  const int tid  = threadIdx.x;
  const int wave = tid >> 6, lane = tid & 63;
  const int l16  = lane & 15, lg = lane >> 4;
  const int wr   = wave >> 1, wc = wave & 1;

  // XCD-aware mapping: all 8 col-blocks of one row-tile land on one XCD
  const int bid = blockIdx.x;            // 0..2559
  const int xcd = bid & 7;
  const int tt  = bid >> 3;              // 0..319
  const int rb  = xcd * 40 + (tt >> 3);  // 0..319
  const int cb  = tt & 7;                // 0..7
  const int rowbase = rb * BM;
  const int colbase = cb * BN;

  // staging precompute: thread t handles 4 slots per matrix per K-step
  // linear LDS offset o = q*4096 + t*16 -> row r = o/128, colbyte = o%128
  // fetch global colbyte ^ ((r&7)<<4) so LDS holds the swizzled layout
  const char* XNc = (const char*)XN;
  const char* CCc = (const char*)CC;
  const char* ag[4];
  const char* bg[4];
  int lds_off[4];
#pragma unroll
  for (int q = 0; q < 4; ++q) {
    const int r   = q * 32 + (tid >> 3);
    const int cbl = (tid & 7) * 16;
    const int fc  = cbl ^ ((r & 7) << 4);
    ag[q] = XNc + (size_t)(rowbase + r) * (D_FEAT * 2) + fc;
    bg[q] = CCc + (size_t)(colbase + r) * (D_FEAT * 2) + fc;
    lds_off[q] = q * 4096 + tid * 16;
  }

  auto STAGE = [&](int buf) {
#pragma unroll
    for (int q = 0; q < 4; ++q) {
      __builtin_amdgcn_global_load_lds(
          (const __attribute__((address_space(1))) unsigned int*)(ag[q]),
          (__attribute__((address_space(3))) unsigned int*)(smem + buf * 32768 + lds_off[q]),
          16, 0, 0);
      __builtin_amdgcn_global_load_lds(
          (const __attribute__((address_space(1))) unsigned int*)(bg[q]),
          (__attribute__((address_space(3))) unsigned int*)(smem + buf * 32768 + 16384 + lds_off[q]),
          16, 0, 0);
      ag[q] += BK * 2;
      bg[q] += BK * 2;
    }
  };

  // fragment ds_read offsets (swizzled): row stride 128B
  const int swz = (l16 & 7) << 4;
  int aoff[4], boff[4];
#pragma unroll
  for (int i = 0; i < 4; ++i) {
    const int arow = wr * 64 + i * 16 + l16;
    aoff[i] = arow * 128 + ((lg << 4) ^ swz);
    const int brow = wc * 64 + i * 16 + l16;
    boff[i] = brow * 128 + ((lg << 4) ^ swz);
  }

  f32x4 acc[4][4];
#pragma unroll
  for (int i = 0; i < 4; ++i)
#pragma unroll
    for (int j = 0; j < 4; ++j) acc[i][j] = (f32x4){0.f, 0.f, 0.f, 0.f};

  STAGE(0);
  __syncthreads();

  for (int kt = 0; kt < KT; ++kt) {
    const int cur = kt & 1;
    if (kt + 1 < KT) STAGE(cur ^ 1);
    const char* Ab = smem + cur * 32768;
    const char* Bb = Ab + 16384;
#pragma unroll
    for (int s = 0; s < 2; ++s) {
      const int sx = s << 6;  // second 32-wide substep: XOR bit6 of col
      short8 av[4], bv[4];
#pragma unroll
      for (int i = 0; i < 4; ++i) av[i] = *(const short8*)(Ab + (aoff[i] ^ sx));
#pragma unroll
      for (int j = 0; j < 4; ++j) bv[j] = *(const short8*)(Bb + (boff[j] ^ sx));
#pragma unroll
      for (int i = 0; i < 4; ++i)
#pragma unroll
        for (int j = 0; j < 4; ++j)
          acc[i][j] = __builtin_amdgcn_mfma_f32_16x16x32_bf16(av[i], bv[j], acc[i][j], 0, 0, 0);
    }
    __syncthreads();
  }

  // ---- epilogue: diag fixup + per-row (max, sumexp) in base-2 over 128 cols ----
  const float ws2 = wp[0] * LOG2E;
  const float b2  = bp[0] * LOG2E;
  float2* red = (float2*)smem;  // [128][2], reuses As[0] (safe after final barrier)

#pragma unroll
  for (int i = 0; i < 4; ++i) {
#pragma unroll
    for (int rr = 0; rr < 4; ++rr) {
      const int lrow = wr * 64 + i * 16 + lg * 4 + rr;  // 0..127
      const int R = rowbase + lrow;
      const int n = R / M_UTT;
      float l2[4];
#pragma unroll
      for (int j = 0; j < 4; ++j) {
        float sim = acc[i][j][rr];
        const int gc = colbase + wc * 64 + j * 16 + l16;
        if (gc == n) {
          sim = (40.f * sim - 1.f) * (1.f / 39.f);  // exclusive centroid, ||xn||=1
          picked2[R] = fmaf(ws2, sim, b2);
        }
        l2[j] = fmaf(ws2, sim, b2);
      }
      float mx = fmaxf(fmaxf(l2[0], l2[1]), fmaxf(l2[2], l2[3]));
#pragma unroll
      for (int d = 1; d < 16; d <<= 1) mx = fmaxf(mx, __shfl_xor(mx, d, 64));
      float s = exp2f(l2[0] - mx) + exp2f(l2[1] - mx) +
                exp2f(l2[2] - mx) + exp2f(l2[3] - mx);
#pragma unroll
      for (int d = 1; d < 16; d <<= 1) s += __shfl_xor(s, d, 64);
      if (l16 == 0) red[lrow * 2 + wc] = make_float2(mx, s);
    }
  }
  __syncthreads();
  if (tid < 128) {
    const float2 p0 = red[tid * 2 + 0];
    const float2 p1 = red[tid * 2 + 1];
    const float m2 = fmaxf(p0.x, p1.x);
    const float ss = p0.y * exp2f(p0.x - m2) + p1.y * exp2f(p1.x - m2);
    ppart[(size_t)(rowbase + tid) * 8 + cb] = make_float2(m2, ss);
  }
}

// ---------------- Kernel 4: combine 8 col-block partials -> row loss ----------------
__global__ __launch_bounds__(256) void k_combine(const float2* __restrict__ pp,
                                                 const float* __restrict__ picked2,
                                                 float* __restrict__ rowloss) {
  const int R = blockIdx.x * 256 + threadIdx.x;
  const float2* p = pp + (size_t)R * 8;
  float2 v[8];
#pragma unroll
  for (int j = 0; j < 8; ++j) v[j] = p[j];
  float m2 = v[0].x;
#pragma unroll
  for (int j = 1; j < 8; ++j) m2 = fmaxf(m2, v[j].x);
  float s = 0.f;
#pragma unroll
  for (int j = 0; j < 8; ++j) s += v[j].y * exp2f(v[j].x - m2);
  const float lse2 = m2 + log2f(s);
  rowloss[R] = (lse2 - picked2[R]) * LN2;
}

// ---------------- Kernel 5: mean over all 40960 rows ----------------
__global__ __launch_bounds__(512) void k_reduce(const float* __restrict__ rowloss,
                                                float* __restrict__ out) {
  const int t = threadIdx.x;
  double s = 0.0;
  for (int i = t; i < NROWS; i += 512) s += (double)rowloss[i];
  __shared__ double sm[512];
  sm[t] = s;
  __syncthreads();
  for (int off = 256; off > 0; off >>= 1) {
    if (t < off) sm[t] += sm[t + off];
    __syncthreads();
  }
  if (t == 0) out[0] = (float)(sm[0] / (double)NROWS);
}

extern "C" void kernel_launch(void* const* d_in, const int* in_sizes, int n_in,
                              void* d_out, int out_size, void* d_ws, size_t ws_size,
                              hipStream_t stream) {
  const float* x = (const float*)d_in[0];
  const float* w = (const float*)d_in[1];
  const float* b = (const float*)d_in[2];
  char* ws = (char*)d_ws;
  size_t off = 0;
  __hip_bfloat16* xn = (__hip_bfloat16*)(ws + off); off += (size_t)NROWS * D_FEAT * 2;
  __hip_bfloat16* cc = (__hip_bfloat16*)(ws + off); off += (size_t)N_SPK * D_FEAT * 2;
  float2* ppart      = (float2*)(ws + off);         off += (size_t)NROWS * 8 * sizeof(float2);
  float* picked2     = (float*)(ws + off);          off += (size_t)NROWS * sizeof(float);
  float* rowloss     = (float*)(ws + off);          off += (size_t)NROWS * sizeof(float);
  float* out = (float*)d_out;

  k_normalize<<<NROWS, 256, 0, stream>>>(x, xn);
  k_centroid<<<N_SPK, 256, 0, stream>>>(xn, cc);
  k_gemm_part<<<(NROWS / BM) * (N_SPK / BN), 256, 0, stream>>>(xn, cc, w, b, ppart, picked2);
  k_combine<<<NROWS / 256, 256, 0, stream>>>(ppart, picked2, rowloss);
  k_reduce<<<1, 512, 0, stream>>>(rowloss, out);
}